// Round 4
// baseline (1312.993 us; speedup 1.0000x reference)
//
#include <hip/hip_runtime.h>
#include <hip/hip_bf16.h>

// Problem constants
#define NNODES 4096
#define NEDGES 32768
#define CH 96           // 48 scalars + 16*3 vectors
#define EPS 1e-5f
#define INV_SQRT3 0.57735026918962576f
#define ALPHA 0.125f    // 1/sqrt(64)

// Workspace layout (float offsets). 1.50 MB.
#define OFF_MSG 0           // NNODES*96 fp32 node accumulator
#define OFF_ST  393216      // 112 stats: [0..47] sum_s, [48..95] sum_s2, [96..111] sum_v2
#define WS_FLOATS 393328

// sanitize: NaN/inf -> 0 (identity on sane data; boundary use only)
__device__ __forceinline__ float fin(float x) {
  return (x == x && fabsf(x) < 1e30f) ? x : 0.f;
}

// ---------------------------------------------------------------------------
__global__ __launch_bounds__(256) void k0_zero(float* ws, int ws_ok) {
  if (!ws_ok) return;
  int idx = blockIdx.x * 256 + threadIdx.x;
  int stride = gridDim.x * 256;
  for (int i = idx; i < WS_FLOATS; i += stride) ws[i] = 0.f;
}

// ---------------------------------------------------------------------------
// K1: fused per-edge pipeline, 32 edges / block, 256 threads.
//   h = relu(ea @ w1 + b1)   (LDS only)
//   w = dlrelu(h @ w2 + b2)  (registers only)
//   tensor product -> 96-ch message -> global fp32 atomic scatter
// a_lds[e][0..47]  : xs*ss            -> acc[0..47]  out_s partial
// a_lds[e][48..63] : dot(xv,sv)/sqrt3 -> acc[0..47]  out_s partial (lut rows 48..63)
// a_lds[e][64..111]: xs               -> acc[48..63] tmp[k] (w_sv path)
// a_lds[e][112..159]: xv flat 3i+m    -> acc[64+3k+m] (w_vv path)
__global__ __launch_bounds__(256) void k1_fused(const int* eidx,
                                                const float* na,
                                                const float* ea,
                                                const float* esh,
                                                const float* w1,
                                                const float* b1,
                                                const float* w2,
                                                const float* b2,
                                                float* ws, int ws_ok) {
  __shared__ __align__(16) float t_lds[128 * 36];  // ea^T then h^T, [k][e], pad 36
  __shared__ float a_lds[32 * 160];
  __shared__ float acc_lds[32 * 112];
  __shared__ unsigned short lut[4096];
  __shared__ float ss_lds[32];
  __shared__ float sv_lds[32][3];
  __shared__ int dst_lds[32];
  __shared__ int src_lds[32];

  float* msg = ws + OFF_MSG;
  const int e0 = blockIdx.x * 32;
  const int tid = threadIdx.x;

  // LUT: j -> (flag, a-index, acc-index). [0,3072) covers w_ss AND w_vs
  // (a_lds[48..63] holds the dot values; 3072/48 = 64 rows).
  for (int j = tid; j < 4096; j += 256) {
    int flag, ai, oi;
    if (j < 3072) { int i = j / 48; flag = 0; ai = i; oi = j - i * 48; }
    else if (j < 3840) { int t = j - 3072; flag = 0; ai = 64 + (t >> 4); oi = 48 + (t & 15); }
    else { int t = j - 3840; flag = 1; ai = 112 + 3 * (t >> 4); oi = 64 + 3 * (t & 15); }
    lut[j] = (unsigned short)((flag << 15) | (ai << 7) | oi);
  }
  // stage ea^T : t_lds[k][e], vectorized float4 reads
  for (int idx = tid; idx < 32 * 32; idx += 256) {
    int e = idx >> 5, k4 = idx & 31;
    float4 v = *(const float4*)(ea + (size_t)(e0 + e) * 128 + k4 * 4);
    t_lds[(k4 * 4 + 0) * 36 + e] = fin(v.x);
    t_lds[(k4 * 4 + 1) * 36 + e] = fin(v.y);
    t_lds[(k4 * 4 + 2) * 36 + e] = fin(v.z);
    t_lds[(k4 * 4 + 3) * 36 + e] = fin(v.w);
  }
  // edge meta + int64-vs-int32 edge_index detection (layout-proof indexing)
  if (tid < 32) {
    int o = 0;
    for (int i = 1; i < 256; i += 2) o |= eidx[i];   // int64-LE => all high halves 0
    const int is64 = (o == 0);
    int e = e0 + tid;
    int s = is64 ? eidx[2 * e] : eidx[e];
    int d = is64 ? eidx[2 * (NEDGES + e)] : eidx[NEDGES + e];
    src_lds[tid] = s & (NNODES - 1);
    dst_lds[tid] = d & (NNODES - 1);
    float4 sh = *(const float4*)(esh + (size_t)e * 4);
    ss_lds[tid] = fin(sh.x);
    sv_lds[tid][0] = fin(sh.y);
    sv_lds[tid][1] = fin(sh.z);
    sv_lds[tid][2] = fin(sh.w);
  }
  __syncthreads();

  // per-edge activation vectors
  for (int idx = tid; idx < 32 * 160; idx += 256) {
    int e = idx / 160; int i = idx - e * 160;
    const float* x = na + (size_t)src_lds[e] * CH;
    float v;
    if (i < 48) v = x[i] * ss_lds[e];
    else if (i < 64) {
      int ii = i - 48;
      v = (x[48 + 3 * ii + 0] * sv_lds[e][0] +
           x[48 + 3 * ii + 1] * sv_lds[e][1] +
           x[48 + 3 * ii + 2] * sv_lds[e][2]) * INV_SQRT3;
    } else if (i < 112) v = x[i - 64];
    else v = x[48 + (i - 112)];
    a_lds[e * 160 + i] = fin(v);
  }
  for (int idx = tid; idx < 32 * 112; idx += 256) acc_lds[idx] = 0.f;

  // ---- GEMM1 in registers: thread (eg,jg) -> edges eg*4..+3, cols jg*4..+3
  const int eg = tid >> 5;
  const int jg = tid & 31;
  const float* ap = t_lds + eg * 4;

  float hreg[16];
#pragma unroll
  for (int i = 0; i < 16; i++) hreg[i] = 0.f;
  {
    const float* bp = w1 + jg * 4;
#pragma unroll 2
    for (int k = 0; k < 128; k++) {
      float4 a = *(const float4*)(ap + k * 36);
      float4 b = *(const float4*)(bp + (size_t)k * 128);
      float av[4] = {a.x, a.y, a.z, a.w};
      float bv[4] = {b.x, b.y, b.z, b.w};
#pragma unroll
      for (int ee = 0; ee < 4; ee++)
#pragma unroll
        for (int jj = 0; jj < 4; jj++) hreg[ee * 4 + jj] += av[ee] * bv[jj];
    }
    float4 bb = *(const float4*)(b1 + jg * 4);
    float bv[4] = {bb.x, bb.y, bb.z, bb.w};
#pragma unroll
    for (int ee = 0; ee < 4; ee++)
#pragma unroll
      for (int jj = 0; jj < 4; jj++)
        hreg[ee * 4 + jj] = fin(fmaxf(hreg[ee * 4 + jj] + bv[jj], 0.f));
  }
  __syncthreads();  // all reads of ea^T done
  // write h^T into t_lds: [j][e]
#pragma unroll
  for (int ee = 0; ee < 4; ee++)
#pragma unroll
    for (int jj = 0; jj < 4; jj++)
      t_lds[(jg * 4 + jj) * 36 + eg * 4 + ee] = hreg[ee * 4 + jj];
  __syncthreads();

  // ---- GEMM2 + dlrelu + routed accumulation
  for (int jt = 0; jt < 16; jt++) {
    const int j0 = jt * 256;
    float acc[32];
#pragma unroll
    for (int i = 0; i < 32; i++) acc[i] = 0.f;
    const float* bp = w2 + j0 + jg * 4;
#pragma unroll 2
    for (int k = 0; k < 128; k++) {
      float4 a = *(const float4*)(ap + k * 36);
      float4 wA = *(const float4*)(bp + (size_t)k * 4096);
      float4 wB = *(const float4*)(bp + (size_t)k * 4096 + 128);
      float av[4] = {a.x, a.y, a.z, a.w};
      float b0[4] = {wA.x, wA.y, wA.z, wA.w};
      float b1v[4] = {wB.x, wB.y, wB.z, wB.w};
#pragma unroll
      for (int ee = 0; ee < 4; ee++) {
#pragma unroll
        for (int jj = 0; jj < 4; jj++) {
          acc[ee * 8 + jj]     += av[ee] * b0[jj];
          acc[ee * 8 + 4 + jj] += av[ee] * b1v[jj];
        }
      }
    }
#pragma unroll
    for (int half = 0; half < 2; half++) {
      int jc0 = j0 + jg * 4 + half * 128;
      float4 bb = *(const float4*)(b2 + jc0);
      float bv[4] = {bb.x, bb.y, bb.z, bb.w};
#pragma unroll
      for (int jj = 0; jj < 4; jj++) {
        unsigned short ent = lut[jc0 + jj];
        int oi = ent & 127, ai = (ent >> 7) & 255, flag = ent >> 15;
#pragma unroll
        for (int ee = 0; ee < 4; ee++) {
          float g = fin(acc[ee * 8 + half * 4 + jj] + bv[jj]);
          float w = (fabsf(g) <= 10.f) ? g : 0.01f * g;
          int e = eg * 4 + ee;
          if (!flag) {
            atomicAdd(&acc_lds[e * 112 + oi], a_lds[e * 160 + ai] * w);
          } else {
            atomicAdd(&acc_lds[e * 112 + oi + 0], a_lds[e * 160 + ai + 0] * w);
            atomicAdd(&acc_lds[e * 112 + oi + 1], a_lds[e * 160 + ai + 1] * w);
            atomicAdd(&acc_lds[e * 112 + oi + 2], a_lds[e * 160 + ai + 2] * w);
          }
        }
      }
    }
  }
  __syncthreads();

  // per-edge message -> scatter into node accumulator
  if (ws_ok) {
    for (int idx = tid; idx < 32 * 96; idx += 256) {
      int e = idx / 96; int c = idx - e * 96;
      float val;
      if (c < 48) val = ALPHA * acc_lds[e * 112 + c];
      else {
        int t = c - 48; int k = t / 3; int m = t - k * 3;
        val = ALPHA * (acc_lds[e * 112 + 48 + k] * sv_lds[e][m] +
                       ss_lds[e] * acc_lds[e * 112 + 64 + 3 * k + m]);
      }
      atomicAdd(msg + (size_t)dst_lds[e] * CH + c, fin(val));
    }
  }
}

// ---------------------------------------------------------------------------
// K2: column-wise BN statistics over out = msg + node_attr
__global__ __launch_bounds__(256) void k2_stats(const float* na, float* ws, int ws_ok) {
  __shared__ float part[112];
  const float* msg = ws + OFF_MSG;
  float* st = ws + OFF_ST;
  for (int i = threadIdx.x; i < 112; i += 256) part[i] = 0.f;
  __syncthreads();
  if (ws_ok) {
    int stride = gridDim.x * 256;
    for (int idx = blockIdx.x * 256 + threadIdx.x; idx < NNODES * CH; idx += stride) {
      int c = idx % CH;
      float t = fin(msg[idx] + fin(na[idx]));
      if (c < 48) { atomicAdd(&part[c], t); atomicAdd(&part[48 + c], t * t); }
      else { int k = (c - 48) / 3; atomicAdd(&part[96 + k], t * t); }
    }
    __syncthreads();
    for (int i = threadIdx.x; i < 112; i += 256) atomicAdd(&st[i], part[i]);
  }
}

// ---------------------------------------------------------------------------
// K3: normalize and emit fp32
__global__ __launch_bounds__(256) void k3_final(const float* na,
                                                const float* bnw,
                                                const float* bnb,
                                                const float* ws,
                                                float* out, int ws_ok) {
  __shared__ float mean_s[48], scale_s[48], bias_s[48], scale_v[16];
  const float* msg = ws + OFF_MSG;
  const float* st = ws + OFF_ST;
  const int tid = threadIdx.x;
  if (tid < 48) {
    float s1 = ws_ok ? fin(st[tid]) : 0.f;
    float s2 = ws_ok ? fin(st[48 + tid]) : 0.f;
    float m = s1 * (1.f / NNODES);
    float var = fmaxf(s2 * (1.f / NNODES) - m * m, 0.f);
    mean_s[tid] = m;
    scale_s[tid] = rsqrtf(var + EPS) * fin(bnw[tid]);
    bias_s[tid] = fin(bnb[tid]);
  } else if (tid < 64) {
    int k = tid - 48;
    float s2 = ws_ok ? fin(st[96 + k]) : 0.f;
    scale_v[k] = rsqrtf(fmaxf(s2 * (1.f / (3.f * NNODES)), 0.f) + EPS) * fin(bnw[48 + k]);
  }
  __syncthreads();
  int stride = gridDim.x * 256;
  for (int idx = blockIdx.x * 256 + tid; idx < NNODES * CH; idx += stride) {
    int c = idx % CH;
    float t = fin((ws_ok ? msg[idx] : 0.f) + fin(na[idx]));
    float o;
    if (c < 48) o = (t - mean_s[c]) * scale_s[c] + bias_s[c];
    else { int k = (c - 48) / 3; o = t * scale_v[k]; }
    out[idx] = fin(o);
  }
}

// ---------------------------------------------------------------------------
extern "C" void kernel_launch(void* const* d_in, const int* in_sizes, int n_in,
                              void* d_out, int out_size, void* d_ws, size_t ws_size,
                              hipStream_t stream) {
  const float* na  = (const float*)d_in[0];
  const int* eidx  = (const int*)d_in[1];
  const float* ea  = (const float*)d_in[2];
  const float* esh = (const float*)d_in[3];
  const float* w1  = (const float*)d_in[4];
  const float* b1  = (const float*)d_in[5];
  const float* w2  = (const float*)d_in[6];
  const float* b2  = (const float*)d_in[7];
  const float* bnw = (const float*)d_in[8];
  const float* bnb = (const float*)d_in[9];
  float* out = (float*)d_out;
  float* ws = (float*)d_ws;
  const int ws_ok = (ws_size >= (size_t)WS_FLOATS * 4) ? 1 : 0;

  hipLaunchKernelGGL(k0_zero,  dim3(512), dim3(256), 0, stream, ws, ws_ok);
  hipLaunchKernelGGL(k1_fused, dim3(NEDGES / 32), dim3(256), 0, stream,
                     eidx, na, ea, esh, w1, b1, w2, b2, ws, ws_ok);
  hipLaunchKernelGGL(k2_stats, dim3(512), dim3(256), 0, stream, na, ws, ws_ok);
  hipLaunchKernelGGL(k3_final, dim3(512), dim3(256), 0, stream, na, bnw, bnb, ws, out, ws_ok);
}

// Round 5
// 1006.971 us; speedup vs baseline: 1.3039x; 1.3039x over previous
//
#include <hip/hip_runtime.h>
#include <hip/hip_bf16.h>

// Problem constants
#define NNODES 4096
#define NEDGES 32768
#define CH 96
#define EPS 1e-5f
#define INV_SQRT3 0.57735026918962576f
#define ALPHA 0.125f

#define EB 64                 // edges per block
#define NBLK (NEDGES / EB)    // 512

// ws layout: msg [0,393216) fp32, stats [393216,393328) fp32,
// then bf16 fragment mirrors at float index 393344 (byte 1573376, 16B aligned)
#define OFF_MSG 0
#define OFF_ST  393216
#define OFF_WSB 393344
#define WSB_W2_U16 (OFF_WSB * 2)                // ushort index: w2 frags, 524288 u16 (1 MB)
#define WSB_W1_U16 (WSB_W2_U16 + 524288)        // w1 frags, 16384 u16 (32 KB)
#define WS_BYTES1 (393328 * 4)                  // msg+stats
#define WS_BYTES2 (393344 * 4 + 524288 * 2 + 16384 * 2)  // + frag mirrors = 2654720 B

typedef __attribute__((ext_vector_type(8))) short short8;
typedef __attribute__((ext_vector_type(4))) float floatx4;

// fp32 -> bf16 RNE
__device__ __forceinline__ unsigned short f2bf(float f) {
  union { float f; unsigned int u; } v; v.f = f;
  return (unsigned short)((v.u + 0x7FFFu + ((v.u >> 16) & 1u)) >> 16);
}
__device__ __forceinline__ float fin(float x) {
  return (x == x && fabsf(x) < 1e30f) ? x : 0.f;
}

// ---------------------------------------------------------------------------
// K0: zero msg+stats; pack w1/w2 into bf16 MFMA B-fragment order.
// Frag layout: group (T,s) = (16-col tile, 32-k step); lane l holds
// B[k = s*32 + (l>>4)*8 + j][n = T*16 + (l&15)], j=0..7 -> 16 B per lane.
__global__ __launch_bounds__(256) void k0_prep(const float* w1, const float* w2,
                                               float* ws, int ok1, int ok2) {
  int p = blockIdx.x * 256 + threadIdx.x;   // 65536 threads
  unsigned short* wsu = (unsigned short*)ws;
  if (ok2) {
    {
      int T = p >> 8, s = (p >> 6) & 3, lane = p & 63;
      int col = T * 16 + (lane & 15);
      int kb = s * 32 + (lane >> 4) * 8;
      const float* src = w2 + (size_t)kb * 4096 + col;
      unsigned int r[4];
#pragma unroll
      for (int jj = 0; jj < 4; jj++) {
        unsigned int lo = f2bf(src[(size_t)(2 * jj + 0) * 4096]);
        unsigned int hi = f2bf(src[(size_t)(2 * jj + 1) * 4096]);
        r[jj] = lo | (hi << 16);
      }
      *(uint4*)(wsu + WSB_W2_U16 + (size_t)p * 8) = make_uint4(r[0], r[1], r[2], r[3]);
    }
    if (p < 2048) {
      int T = p >> 8, s = (p >> 6) & 3, lane = p & 63;
      int col = T * 16 + (lane & 15);
      int kb = s * 32 + (lane >> 4) * 8;
      const float* src = w1 + (size_t)kb * 128 + col;
      unsigned int r[4];
#pragma unroll
      for (int jj = 0; jj < 4; jj++) {
        unsigned int lo = f2bf(src[(size_t)(2 * jj + 0) * 128]);
        unsigned int hi = f2bf(src[(size_t)(2 * jj + 1) * 128]);
        r[jj] = lo | (hi << 16);
      }
      *(uint4*)(wsu + WSB_W1_U16 + (size_t)p * 8) = make_uint4(r[0], r[1], r[2], r[3]);
    }
  }
  if (ok1) for (int i = p; i < 393328; i += 65536) ws[i] = 0.f;
}

// ---------------------------------------------------------------------------
// K1: fused edge pipeline with MFMA. 64 edges/block, 256 threads, 512 blocks.
__global__ __launch_bounds__(256) void k1_fused(const int* eidx, const float* na,
                                                const float* ea, const float* esh,
                                                const float* b1g, const float* b2g,
                                                float* ws, int ok2) {
  if (!ok2) return;  // uniform across grid
  __shared__ __align__(16) unsigned short Bfrag[16384];   // 32 KB: [nt8][ks4][lane64][j8]
  __shared__ __align__(16) unsigned short Afrag[8192];    // 16 KB: [mt4][ks4][lane64][j8]
  __shared__ __align__(16) unsigned short hscr[64 * 136]; // padded [e][k] bf16
  __shared__ float a_lds[64 * 161];
  __shared__ float acc_lds[64 * 113];
  __shared__ float ss_lds[64];
  __shared__ float sv_lds[64][3];
  __shared__ int dst_lds[64];
  __shared__ int src_lds[64];

  const int tid = threadIdx.x;
  const int lane = tid & 63;
  const int q = lane >> 4;
  const int cl = lane & 15;
  const int wv = tid >> 6;
  const int e0 = blockIdx.x * EB;
  unsigned short* wsu = (unsigned short*)ws;
  float* msg = ws;

  // ---- phase 0: edge meta (+ int64/int32 edge_index detection)
  if (tid < 64) {
    int o = 0;
    for (int i = 1; i < 256; i += 2) o |= eidx[i];
    const int is64 = (o == 0);
    int e = e0 + tid;
    int s = is64 ? eidx[2 * e] : eidx[e];
    int d = is64 ? eidx[2 * (NEDGES + e)] : eidx[NEDGES + e];
    src_lds[tid] = s & (NNODES - 1);
    dst_lds[tid] = d & (NNODES - 1);
    float4 sh = *(const float4*)(esh + (size_t)e * 4);
    ss_lds[tid] = sh.x;
    sv_lds[tid][0] = sh.y; sv_lds[tid][1] = sh.z; sv_lds[tid][2] = sh.w;
  }
  // ---- phase 0b: stage ea -> hscr (bf16, padded stride 136)
  for (int idx = tid; idx < EB * 32; idx += 256) {
    int e = idx >> 5, k4 = idx & 31;
    float4 v = *(const float4*)(ea + (size_t)(e0 + e) * 128 + k4 * 4);
    ushort4 o;
    o.x = f2bf(v.x); o.y = f2bf(v.y); o.z = f2bf(v.z); o.w = f2bf(v.w);
    *(ushort4*)&hscr[e * 136 + k4 * 4] = o;
  }
  __syncthreads();

  // ---- phase 1: gather per-edge activation vectors (fp32)
  for (int idx = tid; idx < EB * 160; idx += 256) {
    int e = idx / 160, i = idx - e * 160;
    const float* x = na + (size_t)src_lds[e] * CH;
    float v;
    if (i < 48) v = x[i] * ss_lds[e];
    else if (i < 64) {
      int ii = i - 48;
      v = (x[48 + 3 * ii] * sv_lds[e][0] + x[49 + 3 * ii] * sv_lds[e][1] +
           x[50 + 3 * ii] * sv_lds[e][2]) * INV_SQRT3;
    } else if (i < 112) v = x[i - 64];
    else v = x[48 + (i - 112)];
    a_lds[e * 161 + i] = v;
  }
  for (int idx = tid; idx < EB * 113; idx += 256) acc_lds[idx] = 0.f;
  // ---- phase 1b: Afrag <- hscr (ea fragments)
#pragma unroll
  for (int it = 0; it < 4; it++) {
    int slot = tid + it * 256;
    int g = slot >> 6, l2 = slot & 63;
    int m = (g >> 2) * 16 + (l2 & 15);
    int kb = (g & 3) * 32 + (l2 >> 4) * 8;
    *(short8*)&Afrag[slot * 8] = *(const short8*)&hscr[m * 136 + kb];
  }
  // ---- phase 1c: Bfrag <- w1 fragments (global, pre-packed)
  {
    const uint4* w1f = (const uint4*)(wsu + WSB_W1_U16);
#pragma unroll
    for (int it = 0; it < 8; it++) {
      int idx = tid + it * 256;
      *(uint4*)&Bfrag[idx * 8] = w1f[idx];
    }
  }
  __syncthreads();

  // ---- phase 2: GEMM1 via MFMA: h = relu(ea @ w1 + b1) -> hscr bf16
  {
#pragma unroll
    for (int t = 0; t < 2; t++) {
      int nt = wv * 2 + t;
      int hcol = nt * 16 + cl;
      float hb = b1g[hcol];
      floatx4 hacc[4];
#pragma unroll
      for (int mt = 0; mt < 4; mt++) hacc[mt] = (floatx4)(0.f);
#pragma unroll
      for (int ks = 0; ks < 4; ks++) {
        short8 bfr = *(const short8*)&Bfrag[((nt * 4 + ks) * 64 + lane) * 8];
#pragma unroll
        for (int mt = 0; mt < 4; mt++) {
          short8 afr = *(const short8*)&Afrag[((mt * 4 + ks) * 64 + lane) * 8];
          hacc[mt] = __builtin_amdgcn_mfma_f32_16x16x32_bf16(afr, bfr, hacc[mt], 0, 0, 0);
        }
      }
#pragma unroll
      for (int mt = 0; mt < 4; mt++)
#pragma unroll
        for (int r = 0; r < 4; r++) {
          int e = mt * 16 + q * 4 + r;
          hscr[e * 136 + hcol] = f2bf(fmaxf(hacc[mt][r] + hb, 0.f));
        }
    }
  }
  __syncthreads();

  // ---- phase 3: Afrag <- hscr (h fragments)
#pragma unroll
  for (int it = 0; it < 4; it++) {
    int slot = tid + it * 256;
    int g = slot >> 6, l2 = slot & 63;
    int m = (g >> 2) * 16 + (l2 & 15);
    int kb = (g & 3) * 32 + (l2 >> 4) * 8;
    *(short8*)&Afrag[slot * 8] = *(const short8*)&hscr[m * 136 + kb];
  }
  __syncthreads();

  // ---- phase 4: A fragments -> registers (held across entire jt loop)
  short8 areg[16];
#pragma unroll
  for (int g = 0; g < 16; g++) areg[g] = *(const short8*)&Afrag[(g * 64 + lane) * 8];

  // ---- phase 5: jt loop over 32 column-panels of 128
  const uint4* wsb = (const uint4*)(wsu + WSB_W2_U16);
  for (int jt = 0; jt < 32; jt++) {
    __syncthreads();   // prior iter's Bfrag reads done
#pragma unroll
    for (int it = 0; it < 8; it++) {
      int idx = tid + it * 256;
      *(uint4*)&Bfrag[idx * 8] = wsb[jt * 2048 + idx];
    }
    __syncthreads();   // Bfrag staged
#pragma unroll
    for (int t = 0; t < 2; t++) {
      int nt = wv * 2 + t;
      int j = jt * 128 + nt * 16 + cl;
      float bias = b2g[j];
      int cls, ai, oi;
      if (j < 3072)      { ai = j / 48; oi = j - ai * 48; cls = 0; }
      else if (j < 3840) { int tt = j - 3072; ai = 64 + (tt >> 4); oi = 48 + (tt & 15); cls = 0; }
      else               { int tt = j - 3840; ai = 112 + 3 * (tt >> 4); oi = 64 + 3 * (tt & 15); cls = 1; }
      floatx4 acc[4];
#pragma unroll
      for (int mt = 0; mt < 4; mt++) acc[mt] = (floatx4)(0.f);
#pragma unroll
      for (int ks = 0; ks < 4; ks++) {
        short8 bfr = *(const short8*)&Bfrag[((nt * 4 + ks) * 64 + lane) * 8];
#pragma unroll
        for (int mt = 0; mt < 4; mt++)
          acc[mt] = __builtin_amdgcn_mfma_f32_16x16x32_bf16(areg[mt * 4 + ks], bfr, acc[mt], 0, 0, 0);
      }
#pragma unroll
      for (int mt = 0; mt < 4; mt++) {
        int ebase = mt * 16 + q * 4;
#pragma unroll
        for (int r = 0; r < 4; r++) {
          int e = ebase + r;
          float g = acc[mt][r] + bias;
          float w = (fabsf(g) <= 10.f) ? g : 0.01f * g;
          if (cls == 0) {
            atomicAdd(&acc_lds[e * 113 + oi], a_lds[e * 161 + ai] * w);
          } else {
            atomicAdd(&acc_lds[e * 113 + oi + 0], a_lds[e * 161 + ai + 0] * w);
            atomicAdd(&acc_lds[e * 113 + oi + 1], a_lds[e * 161 + ai + 1] * w);
            atomicAdd(&acc_lds[e * 113 + oi + 2], a_lds[e * 161 + ai + 2] * w);
          }
        }
      }
    }
  }
  __syncthreads();

  // ---- phase 6: build 96-ch message, scatter to node accumulator
  for (int idx = tid; idx < EB * 96; idx += 256) {
    int e = idx / 96, c = idx - e * 96;
    float val;
    if (c < 48) val = ALPHA * acc_lds[e * 113 + c];
    else {
      int t2 = c - 48; int k = t2 / 3; int m = t2 - k * 3;
      val = ALPHA * (acc_lds[e * 113 + 48 + k] * sv_lds[e][m] +
                     ss_lds[e] * acc_lds[e * 113 + 64 + 3 * k + m]);
    }
    atomicAdd(msg + (size_t)dst_lds[e] * CH + c, val);
  }
}

// ---------------------------------------------------------------------------
// K2: column-wise BN statistics over out = msg + node_attr
__global__ __launch_bounds__(256) void k2_stats(const float* na, float* ws, int ok1) {
  __shared__ float part[112];
  const float* msg = ws + OFF_MSG;
  float* st = ws + OFF_ST;
  for (int i = threadIdx.x; i < 112; i += 256) part[i] = 0.f;
  __syncthreads();
  if (ok1) {
    int stride = gridDim.x * 256;
    for (int idx = blockIdx.x * 256 + threadIdx.x; idx < NNODES * CH; idx += stride) {
      int c = idx % CH;
      float t = msg[idx] + na[idx];
      if (c < 48) { atomicAdd(&part[c], t); atomicAdd(&part[48 + c], t * t); }
      else { int k = (c - 48) / 3; atomicAdd(&part[96 + k], t * t); }
    }
    __syncthreads();
    for (int i = threadIdx.x; i < 112; i += 256) atomicAdd(&st[i], part[i]);
  }
}

// ---------------------------------------------------------------------------
// K3: normalize and emit fp32
__global__ __launch_bounds__(256) void k3_final(const float* na, const float* bnw,
                                                const float* bnb, const float* ws,
                                                float* out, int ok1) {
  __shared__ float mean_s[48], scale_s[48], bias_s[48], scale_v[16];
  const float* msg = ws + OFF_MSG;
  const float* st = ws + OFF_ST;
  const int tid = threadIdx.x;
  if (tid < 48) {
    float s1 = ok1 ? fin(st[tid]) : 0.f;
    float s2 = ok1 ? fin(st[48 + tid]) : 0.f;
    float m = s1 * (1.f / NNODES);
    float var = fmaxf(s2 * (1.f / NNODES) - m * m, 0.f);
    mean_s[tid] = m;
    scale_s[tid] = rsqrtf(var + EPS) * bnw[tid];
    bias_s[tid] = bnb[tid];
  } else if (tid < 64) {
    int k = tid - 48;
    float s2 = ok1 ? fin(st[96 + k]) : 0.f;
    scale_v[k] = rsqrtf(fmaxf(s2 * (1.f / (3.f * NNODES)), 0.f) + EPS) * bnw[48 + k];
  }
  __syncthreads();
  int stride = gridDim.x * 256;
  for (int idx = blockIdx.x * 256 + tid; idx < NNODES * CH; idx += stride) {
    int c = idx % CH;
    float t = (ok1 ? msg[idx] : 0.f) + na[idx];
    float o;
    if (c < 48) o = (t - mean_s[c]) * scale_s[c] + bias_s[c];
    else { int k = (c - 48) / 3; o = t * scale_v[k]; }
    out[idx] = fin(o);
  }
}

// ---------------------------------------------------------------------------
extern "C" void kernel_launch(void* const* d_in, const int* in_sizes, int n_in,
                              void* d_out, int out_size, void* d_ws, size_t ws_size,
                              hipStream_t stream) {
  const float* na  = (const float*)d_in[0];
  const int* eidx  = (const int*)d_in[1];
  const float* ea  = (const float*)d_in[2];
  const float* esh = (const float*)d_in[3];
  const float* w1  = (const float*)d_in[4];
  const float* b1  = (const float*)d_in[5];
  const float* w2  = (const float*)d_in[6];
  const float* b2  = (const float*)d_in[7];
  const float* bnw = (const float*)d_in[8];
  const float* bnb = (const float*)d_in[9];
  float* out = (float*)d_out;
  float* ws = (float*)d_ws;
  const int ok1 = (ws_size >= (size_t)WS_BYTES1) ? 1 : 0;
  const int ok2 = (ws_size >= (size_t)WS_BYTES2) ? 1 : 0;

  hipLaunchKernelGGL(k0_prep,  dim3(256), dim3(256), 0, stream, w1, w2, ws, ok1, ok2);
  hipLaunchKernelGGL(k1_fused, dim3(NBLK), dim3(256), 0, stream,
                     eidx, na, ea, esh, b1, b2, ws, ok2);
  hipLaunchKernelGGL(k2_stats, dim3(512), dim3(256), 0, stream, na, ws, ok1);
  hipLaunchKernelGGL(k3_final, dim3(512), dim3(256), 0, stream, na, bnw, bnb, ws, out, ok1);
}

// Round 6
// 287.094 us; speedup vs baseline: 4.5734x; 3.5075x over previous
//
#include <hip/hip_runtime.h>
#include <hip/hip_bf16.h>

// Problem constants
#define NNODES 4096
#define NEDGES 32768
#define CH 96
#define EPS 1e-5f
#define INV_SQRT3 0.57735026918962576f
#define ALPHA 0.125f

#define EB 32                 // edges per block
#define NBLK (NEDGES / EB)    // 1024

// ws layout: msg [0,393216) fp32, stats [393216,393328) fp32,
// bf16 fragment mirrors at float index 393344 (byte 1573376, 16B aligned)
#define OFF_MSG 0
#define OFF_ST  393216
#define OFF_WSB 393344
#define WSB_W2_U16 (OFF_WSB * 2)                // w2 frags: 524288 u16 (1 MB)
#define WSB_W1_U16 (WSB_W2_U16 + 524288)        // w1 frags: 16384 u16 (32 KB)
#define WS_BYTES1 (393328 * 4)
#define WS_BYTES2 (393344 * 4 + 524288 * 2 + 16384 * 2)

typedef __attribute__((ext_vector_type(8))) short short8;
typedef __attribute__((ext_vector_type(4))) float floatx4;

__device__ __forceinline__ unsigned short f2bf(float f) {
  union { float f; unsigned int u; } v; v.f = f;
  return (unsigned short)((v.u + 0x7FFFu + ((v.u >> 16) & 1u)) >> 16);
}
__device__ __forceinline__ float fin(float x) {
  return (x == x && fabsf(x) < 1e30f) ? x : 0.f;
}
__device__ __forceinline__ float dlrelu(float g) {
  return (fabsf(g) <= 10.f) ? g : 0.01f * g;
}

// ---------------------------------------------------------------------------
// K0: coalesced pack of w1/w2 into MFMA B-fragment order + zero msg/stats.
// Fragment (T,s): lane l holds B[k=s*32+(l>>4)*8+j][n=T*16+(l&15)], j=0..7.
__global__ __launch_bounds__(256) void k0_prep(const float* w1, const float* w2,
                                               float* ws, int ok1, int ok2) {
  __shared__ float tile[128 * 16];
  const int t = threadIdx.x;
  const int b = blockIdx.x;          // 256 blocks; block b = w2 col-tile T=b
  unsigned short* wsu = (unsigned short*)ws;

  if (ok1) {  // zero msg+stats (grid-stride)
    for (int i = b * 256 + t; i < 393328; i += 256 * 256) ws[i] = 0.f;
  }
  if (ok2) {
    // ---- w2 tile T=b: stage 128k x 16col coalesced, emit fragments
    {
      const int T = b;
#pragma unroll
      for (int p = 0; p < 8; p++) {
        int k = p * 16 + (t >> 4), col = t & 15;
        tile[k * 16 + col] = w2[(size_t)k * 4096 + T * 16 + col];
      }
      __syncthreads();
      int s = t >> 6, lane = t & 63, q = (lane >> 4), cl = lane & 15;
      unsigned int r[4];
#pragma unroll
      for (int jj = 0; jj < 4; jj++) {
        int k0 = s * 32 + q * 8 + 2 * jj;
        unsigned int lo = f2bf(tile[k0 * 16 + cl]);
        unsigned int hi = f2bf(tile[(k0 + 1) * 16 + cl]);
        r[jj] = lo | (hi << 16);
      }
      *(uint4*)(wsu + WSB_W2_U16 + ((size_t)(T * 4 + s) * 64 + lane) * 8) =
          make_uint4(r[0], r[1], r[2], r[3]);
    }
    // ---- w1 tiles: blocks 0..7
    if (b < 8) {
      __syncthreads();
      const int T = b;
#pragma unroll
      for (int p = 0; p < 8; p++) {
        int k = p * 16 + (t >> 4), col = t & 15;
        tile[k * 16 + col] = w1[(size_t)k * 128 + T * 16 + col];
      }
      __syncthreads();
      int s = t >> 6, lane = t & 63, q = (lane >> 4), cl = lane & 15;
      unsigned int r[4];
#pragma unroll
      for (int jj = 0; jj < 4; jj++) {
        int k0 = s * 32 + q * 8 + 2 * jj;
        unsigned int lo = f2bf(tile[k0 * 16 + cl]);
        unsigned int hi = f2bf(tile[(k0 + 1) * 16 + cl]);
        r[jj] = lo | (hi << 16);
      }
      *(uint4*)(wsu + WSB_W1_U16 + ((size_t)(T * 4 + s) * 64 + lane) * 8) =
          make_uint4(r[0], r[1], r[2], r[3]);
    }
  }
}

// ---------------------------------------------------------------------------
// K1: fused edge pipeline. 32 edges/block, 256 thr, 1024 blocks, 3 blk/CU.
// Main loop: no barriers, no LDS atomics; B-frags read direct from global L2.
__global__ __launch_bounds__(256, 3) void k1_fused(const int* eidx, const float* na,
                                                   const float* ea, const float* esh,
                                                   const float* b1g, const float* b2g,
                                                   float* ws, int ok2) {
  if (!ok2) return;
  __shared__ __align__(16) unsigned short hscr[EB * 136];  // h bf16, [e][k]
  __shared__ float a_lds[EB * 161];   // activations fp32
  __shared__ float acc_lds[EB * 113]; // reduction target
  __shared__ float ss_lds[EB];
  __shared__ float sv_lds[EB][3];
  __shared__ int dst_lds[EB];
  __shared__ int src_lds[EB];

  const int tid = threadIdx.x;
  const int lane = tid & 63;
  const int q = lane >> 4;
  const int cl = lane & 15;
  const int wv = tid >> 6;
  const int e0 = blockIdx.x * EB;
  unsigned short* wsu = (unsigned short*)ws;
  float* msg = ws;

  // ---- phase 0: edge meta + int64/int32 edge_index detection
  if (tid < EB) {
    int o = 0;
    for (int i = 1; i < 256; i += 2) o |= eidx[i];
    const int is64 = (o == 0);
    int e = e0 + tid;
    int s = is64 ? eidx[2 * e] : eidx[e];
    int d = is64 ? eidx[2 * (NEDGES + e)] : eidx[NEDGES + e];
    src_lds[tid] = s & (NNODES - 1);
    dst_lds[tid] = d & (NNODES - 1);
    float4 sh = *(const float4*)(esh + (size_t)e * 4);
    ss_lds[tid] = sh.x;
    sv_lds[tid][0] = sh.y; sv_lds[tid][1] = sh.z; sv_lds[tid][2] = sh.w;
  }
  __syncthreads();

  // ---- phase 1a: zero reduction buffer
  for (int idx = tid; idx < EB * 113; idx += 256) acc_lds[idx] = 0.f;
  // ---- phase 1b: gather per-edge activations
  // a[e][0..47]=xs*ss  [48..63]=dot/sqrt3  [64..111]=xs  [112..159]=xv
  for (int idx = tid; idx < EB * 160; idx += 256) {
    int e = idx / 160, i = idx - e * 160;
    const float* x = na + (size_t)src_lds[e] * CH;
    float v;
    if (i < 48) v = x[i] * ss_lds[e];
    else if (i < 64) {
      int ii = i - 48;
      v = (x[48 + 3 * ii] * sv_lds[e][0] + x[49 + 3 * ii] * sv_lds[e][1] +
           x[50 + 3 * ii] * sv_lds[e][2]) * INV_SQRT3;
    } else if (i < 112) v = x[i - 64];
    else v = x[48 + (i - 112)];
    a_lds[e * 161 + i] = v;
  }

  // ---- phase 1c: GEMM1  h = relu(ea@w1+b1) -> hscr
  {
    short8 a1[2][4];
#pragma unroll
    for (int mt = 0; mt < 2; mt++)
#pragma unroll
      for (int ks = 0; ks < 4; ks++) {
        const float* src = ea + (size_t)(e0 + mt * 16 + cl) * 128 + ks * 32 + q * 8;
        float4 v0 = *(const float4*)src;
        float4 v1 = *(const float4*)(src + 4);
        union { short8 s; unsigned int u[4]; } pk;
        pk.u[0] = f2bf(v0.x) | ((unsigned)f2bf(v0.y) << 16);
        pk.u[1] = f2bf(v0.z) | ((unsigned)f2bf(v0.w) << 16);
        pk.u[2] = f2bf(v1.x) | ((unsigned)f2bf(v1.y) << 16);
        pk.u[3] = f2bf(v1.z) | ((unsigned)f2bf(v1.w) << 16);
        a1[mt][ks] = pk.s;
      }
    const short8* w1f = (const short8*)(wsu + WSB_W1_U16);
#pragma unroll
    for (int t = 0; t < 2; t++) {
      int nt = wv * 2 + t;
      floatx4 c0 = (floatx4)(0.f), c1 = (floatx4)(0.f);
#pragma unroll
      for (int ks = 0; ks < 4; ks++) {
        short8 bf = w1f[(nt * 4 + ks) * 64 + lane];
        c0 = __builtin_amdgcn_mfma_f32_16x16x32_bf16(a1[0][ks], bf, c0, 0, 0, 0);
        c1 = __builtin_amdgcn_mfma_f32_16x16x32_bf16(a1[1][ks], bf, c1, 0, 0, 0);
      }
      int hcol = nt * 16 + cl;
      float hb = b1g[hcol];
#pragma unroll
      for (int r = 0; r < 4; r++) {
        hscr[(0 * 16 + q * 4 + r) * 136 + hcol] = f2bf(fmaxf(c0[r] + hb, 0.f));
        hscr[(1 * 16 + q * 4 + r) * 136 + hcol] = f2bf(fmaxf(c1[r] + hb, 0.f));
      }
    }
  }
  __syncthreads();

  // ---- phase 2: A fragments (h) -> registers
  short8 areg[2][4];
#pragma unroll
  for (int mt = 0; mt < 2; mt++)
#pragma unroll
    for (int ks = 0; ks < 4; ks++)
      areg[mt][ks] = *(const short8*)&hscr[(mt * 16 + cl) * 136 + ks * 32 + q * 8];

  // ---- phase 3: main loop over column tiles u = 4s+wv (no barriers/atomics)
  float accS[3][2][4], accT[2][4], accV[2][4][3];
#pragma unroll
  for (int c = 0; c < 3; c++)
#pragma unroll
    for (int mt = 0; mt < 2; mt++)
#pragma unroll
      for (int r = 0; r < 4; r++) accS[c][mt][r] = 0.f;
#pragma unroll
  for (int mt = 0; mt < 2; mt++)
#pragma unroll
    for (int r = 0; r < 4; r++) {
      accT[mt][r] = 0.f;
      accV[mt][r][0] = 0.f; accV[mt][r][1] = 0.f; accV[mt][r][2] = 0.f;
    }

  const short8* w2f = (const short8*)(wsu + WSB_W2_U16);

#define GEMM2_TILE(u, WARR)                                                    \
  float WARR[2][4];                                                            \
  {                                                                            \
    int jcol = (u) * 16 + cl;                                                  \
    float bias = b2g[jcol];                                                    \
    floatx4 c0 = (floatx4)(0.f), c1 = (floatx4)(0.f);                          \
    _Pragma("unroll")                                                          \
    for (int ks = 0; ks < 4; ks++) {                                           \
      short8 bf = w2f[((u) * 4 + ks) * 64 + lane];                             \
      c0 = __builtin_amdgcn_mfma_f32_16x16x32_bf16(areg[0][ks], bf, c0, 0, 0, 0); \
      c1 = __builtin_amdgcn_mfma_f32_16x16x32_bf16(areg[1][ks], bf, c1, 0, 0, 0); \
    }                                                                          \
    _Pragma("unroll")                                                          \
    for (int r = 0; r < 4; r++) {                                              \
      WARR[0][r] = dlrelu(c0[r] + bias);                                       \
      WARR[1][r] = dlrelu(c1[r] + bias);                                       \
    }                                                                          \
  }

  // class ss/vs: s in [0,48) -> u < 192
  for (int s = 0; s < 48; s++) {
    int u = 4 * s + wv;
    GEMM2_TILE(u, wva)
    int ai = u / 3;
    int c = u - ai * 3;
    float av[2][4];
#pragma unroll
    for (int mt = 0; mt < 2; mt++)
#pragma unroll
      for (int r = 0; r < 4; r++)
        av[mt][r] = a_lds[(mt * 16 + q * 4 + r) * 161 + ai];
    if (c == 0) {
#pragma unroll
      for (int mt = 0; mt < 2; mt++)
#pragma unroll
        for (int r = 0; r < 4; r++) accS[0][mt][r] += av[mt][r] * wva[mt][r];
    } else if (c == 1) {
#pragma unroll
      for (int mt = 0; mt < 2; mt++)
#pragma unroll
        for (int r = 0; r < 4; r++) accS[1][mt][r] += av[mt][r] * wva[mt][r];
    } else {
#pragma unroll
      for (int mt = 0; mt < 2; mt++)
#pragma unroll
        for (int r = 0; r < 4; r++) accS[2][mt][r] += av[mt][r] * wva[mt][r];
    }
  }
  // class sv: s in [48,60) -> u in [192,240): ai = 64 + (u-192) = u-128
  for (int s = 48; s < 60; s++) {
    int u = 4 * s + wv;
    GEMM2_TILE(u, wvb)
    int ai = u - 128;
#pragma unroll
    for (int mt = 0; mt < 2; mt++)
#pragma unroll
      for (int r = 0; r < 4; r++)
        accT[mt][r] += a_lds[(mt * 16 + q * 4 + r) * 161 + ai] * wvb[mt][r];
  }
  // class vv: s in [60,64) -> u in [240,256): abase = 112 + 3(u-240) = 3u-608
  for (int s = 60; s < 64; s++) {
    int u = 4 * s + wv;
    GEMM2_TILE(u, wvc)
    int ab = 3 * u - 608;
#pragma unroll
    for (int mt = 0; mt < 2; mt++)
#pragma unroll
      for (int r = 0; r < 4; r++) {
        int base = (mt * 16 + q * 4 + r) * 161 + ab;
        accV[mt][r][0] += a_lds[base + 0] * wvc[mt][r];
        accV[mt][r][1] += a_lds[base + 1] * wvc[mt][r];
        accV[mt][r][2] += a_lds[base + 2] * wvc[mt][r];
      }
  }

  // ---- phase 4: cross-wave reduction (one lane owns each (e,oi) per wave)
#pragma unroll
  for (int mt = 0; mt < 2; mt++)
#pragma unroll
    for (int r = 0; r < 4; r++) {
      int e = mt * 16 + q * 4 + r;
#pragma unroll
      for (int c = 0; c < 3; c++)
        atomicAdd(&acc_lds[e * 113 + c * 16 + cl], accS[c][mt][r]);
      atomicAdd(&acc_lds[e * 113 + 48 + cl], accT[mt][r]);
#pragma unroll
      for (int m = 0; m < 3; m++)
        atomicAdd(&acc_lds[e * 113 + 64 + 3 * cl + m], accV[mt][r][m]);
    }
  __syncthreads();

  // ---- phase 5: build 96-ch message, scatter to node accumulator
  for (int idx = tid; idx < EB * 96; idx += 256) {
    int e = idx / 96, c = idx - e * 96;
    float val;
    if (c < 48) val = ALPHA * acc_lds[e * 113 + c];
    else {
      int t2 = c - 48; int k = t2 / 3; int m = t2 - k * 3;
      val = ALPHA * (acc_lds[e * 113 + 48 + k] * sv_lds[e][m] +
                     ss_lds[e] * acc_lds[e * 113 + 64 + 3 * k + m]);
    }
    atomicAdd(msg + (size_t)dst_lds[e] * CH + c, val);
  }
}

// ---------------------------------------------------------------------------
__global__ __launch_bounds__(256) void k2_stats(const float* na, float* ws, int ok1) {
  __shared__ float part[112];
  const float* msg = ws + OFF_MSG;
  float* st = ws + OFF_ST;
  for (int i = threadIdx.x; i < 112; i += 256) part[i] = 0.f;
  __syncthreads();
  if (ok1) {
    int stride = gridDim.x * 256;
    for (int idx = blockIdx.x * 256 + threadIdx.x; idx < NNODES * CH; idx += stride) {
      int c = idx % CH;
      float t = msg[idx] + na[idx];
      if (c < 48) { atomicAdd(&part[c], t); atomicAdd(&part[48 + c], t * t); }
      else { int k = (c - 48) / 3; atomicAdd(&part[96 + k], t * t); }
    }
    __syncthreads();
    for (int i = threadIdx.x; i < 112; i += 256) atomicAdd(&st[i], part[i]);
  }
}

// ---------------------------------------------------------------------------
__global__ __launch_bounds__(256) void k3_final(const float* na, const float* bnw,
                                                const float* bnb, const float* ws,
                                                float* out, int ok1) {
  __shared__ float mean_s[48], scale_s[48], bias_s[48], scale_v[16];
  const float* msg = ws + OFF_MSG;
  const float* st = ws + OFF_ST;
  const int tid = threadIdx.x;
  if (tid < 48) {
    float s1 = ok1 ? fin(st[tid]) : 0.f;
    float s2 = ok1 ? fin(st[48 + tid]) : 0.f;
    float m = s1 * (1.f / NNODES);
    float var = fmaxf(s2 * (1.f / NNODES) - m * m, 0.f);
    mean_s[tid] = m;
    scale_s[tid] = rsqrtf(var + EPS) * bnw[tid];
    bias_s[tid] = bnb[tid];
  } else if (tid < 64) {
    int k = tid - 48;
    float s2 = ok1 ? fin(st[96 + k]) : 0.f;
    scale_v[k] = rsqrtf(fmaxf(s2 * (1.f / (3.f * NNODES)), 0.f) + EPS) * bnw[48 + k];
  }
  __syncthreads();
  int stride = gridDim.x * 256;
  for (int idx = blockIdx.x * 256 + tid; idx < NNODES * CH; idx += stride) {
    int c = idx % CH;
    float t = (ok1 ? msg[idx] : 0.f) + na[idx];
    float o;
    if (c < 48) o = (t - mean_s[c]) * scale_s[c] + bias_s[c];
    else { int k = (c - 48) / 3; o = t * scale_v[k]; }
    out[idx] = fin(o);
  }
}

// ---------------------------------------------------------------------------
extern "C" void kernel_launch(void* const* d_in, const int* in_sizes, int n_in,
                              void* d_out, int out_size, void* d_ws, size_t ws_size,
                              hipStream_t stream) {
  const float* na  = (const float*)d_in[0];
  const int* eidx  = (const int*)d_in[1];
  const float* ea  = (const float*)d_in[2];
  const float* esh = (const float*)d_in[3];
  const float* w1  = (const float*)d_in[4];
  const float* b1  = (const float*)d_in[5];
  const float* w2  = (const float*)d_in[6];
  const float* b2  = (const float*)d_in[7];
  const float* bnw = (const float*)d_in[8];
  const float* bnb = (const float*)d_in[9];
  float* out = (float*)d_out;
  float* ws = (float*)d_ws;
  const int ok1 = (ws_size >= (size_t)WS_BYTES1) ? 1 : 0;
  const int ok2 = (ws_size >= (size_t)WS_BYTES2) ? 1 : 0;

  hipLaunchKernelGGL(k0_prep,  dim3(256), dim3(256), 0, stream, w1, w2, ws, ok1, ok2);
  hipLaunchKernelGGL(k1_fused, dim3(NBLK), dim3(256), 0, stream,
                     eidx, na, ea, esh, b1, b2, ws, ok2);
  hipLaunchKernelGGL(k2_stats, dim3(512), dim3(256), 0, stream, na, ws, ok1);
  hipLaunchKernelGGL(k3_final, dim3(512), dim3(256), 0, stream, na, bnw, bnb, ws, out, ok1);
}

// Round 7
// 200.150 us; speedup vs baseline: 6.5600x; 1.4344x over previous
//
#include <hip/hip_runtime.h>
#include <hip/hip_bf16.h>

// Problem constants
#define NNODES 4096
#define NEDGES 32768
#define CH 96
#define EPS 1e-5f
#define INV_SQRT3 0.57735026918962576f
#define ALPHA 0.125f

#define EB 32
#define NBLK (NEDGES / EB)    // 1024

// ws layout: msg [0,393216) fp32, stats [393216,393328),
// bf16 fragment mirrors at float index 393344
#define OFF_MSG 0
#define OFF_ST  393216
#define OFF_WSB 393344
#define WSB_W2_U16 (OFF_WSB * 2)
#define WSB_W1_U16 (WSB_W2_U16 + 524288)
#define WS_BYTES1 (393328 * 4)
#define WS_BYTES2 (393344 * 4 + 524288 * 2 + 16384 * 2)

typedef __attribute__((ext_vector_type(8))) short short8;
typedef __attribute__((ext_vector_type(4))) float floatx4;

__device__ __forceinline__ unsigned short f2bf(float f) {
  union { float f; unsigned int u; } v; v.f = f;
  return (unsigned short)((v.u + 0x7FFFu + ((v.u >> 16) & 1u)) >> 16);
}
__device__ __forceinline__ float fin(float x) {
  return (x == x && fabsf(x) < 1e30f) ? x : 0.f;
}
__device__ __forceinline__ float dlrelu(float g) {
  return (fabsf(g) <= 10.f) ? g : 0.01f * g;
}

// ---------------------------------------------------------------------------
// K0: pack w1/w2 to MFMA B-frag order (bf16) + zero msg/stats.
__global__ __launch_bounds__(256) void k0_prep(const float* w1, const float* w2,
                                               float* ws, int ok1, int ok2) {
  __shared__ float tile[128 * 16];
  const int t = threadIdx.x;
  const int b = blockIdx.x;
  unsigned short* wsu = (unsigned short*)ws;

  if (ok1) {
    for (int i = b * 256 + t; i < 393328; i += 256 * 256) ws[i] = 0.f;
  }
  if (ok2) {
    {
      const int T = b;
#pragma unroll
      for (int p = 0; p < 8; p++) {
        int k = p * 16 + (t >> 4), col = t & 15;
        tile[k * 16 + col] = w2[(size_t)k * 4096 + T * 16 + col];
      }
      __syncthreads();
      int s = t >> 6, lane = t & 63, q = (lane >> 4), cl = lane & 15;
      unsigned int r[4];
#pragma unroll
      for (int jj = 0; jj < 4; jj++) {
        int k0 = s * 32 + q * 8 + 2 * jj;
        unsigned int lo = f2bf(tile[k0 * 16 + cl]);
        unsigned int hi = f2bf(tile[(k0 + 1) * 16 + cl]);
        r[jj] = lo | (hi << 16);
      }
      *(uint4*)(wsu + WSB_W2_U16 + ((size_t)(T * 4 + s) * 64 + lane) * 8) =
          make_uint4(r[0], r[1], r[2], r[3]);
    }
    if (b < 8) {
      __syncthreads();
      const int T = b;
#pragma unroll
      for (int p = 0; p < 8; p++) {
        int k = p * 16 + (t >> 4), col = t & 15;
        tile[k * 16 + col] = w1[(size_t)k * 128 + T * 16 + col];
      }
      __syncthreads();
      int s = t >> 6, lane = t & 63, q = (lane >> 4), cl = lane & 15;
      unsigned int r[4];
#pragma unroll
      for (int jj = 0; jj < 4; jj++) {
        int k0 = s * 32 + q * 8 + 2 * jj;
        unsigned int lo = f2bf(tile[k0 * 16 + cl]);
        unsigned int hi = f2bf(tile[(k0 + 1) * 16 + cl]);
        r[jj] = lo | (hi << 16);
      }
      *(uint4*)(wsu + WSB_W1_U16 + ((size_t)(T * 4 + s) * 64 + lane) * 8) =
          make_uint4(r[0], r[1], r[2], r[3]);
    }
  }
}

// ---------------------------------------------------------------------------
// K1: fused edge pipeline. 32 edges/block, 256 thr, 1024 blocks, 4 blk/CU.
// B prefetch in rotating register buffers; LDS overlay hscr/acc.
__global__ __launch_bounds__(256, 4) void k1_fused(const int* eidx, const float* na,
                                                   const float* ea, const float* esh,
                                                   const float* b1g, const float* b2g,
                                                   float* ws, int ok2) {
  if (!ok2) return;
  __shared__ float a_lds[EB * 161];                 // 20608 B
  __shared__ __align__(16) char ovl[EB * 113 * 4];  // 14464 B: hscr then acc_lds
  __shared__ float ss_lds[EB];
  __shared__ float sv_lds[EB][3];
  __shared__ int dst_lds[EB];
  __shared__ int src_lds[EB];
  unsigned short* hscr = (unsigned short*)ovl;      // [e][k] stride 136, bf16
  float* acc_lds = (float*)ovl;                     // [e][oi] stride 113

  const int tid = threadIdx.x;
  const int lane = tid & 63;
  const int q = lane >> 4;
  const int cl = lane & 15;
  const int wv = tid >> 6;
  const int e0 = blockIdx.x * EB;
  unsigned short* wsu = (unsigned short*)ws;
  float* msg = ws;

  // ---- phase 0: edge meta + int64/int32 detection
  if (tid < EB) {
    int o = 0;
    for (int i = 1; i < 256; i += 2) o |= eidx[i];
    const int is64 = (o == 0);
    int e = e0 + tid;
    int s = is64 ? eidx[2 * e] : eidx[e];
    int d = is64 ? eidx[2 * (NEDGES + e)] : eidx[NEDGES + e];
    src_lds[tid] = s & (NNODES - 1);
    dst_lds[tid] = d & (NNODES - 1);
    float4 sh = *(const float4*)(esh + (size_t)e * 4);
    ss_lds[tid] = sh.x;
    sv_lds[tid][0] = sh.y; sv_lds[tid][1] = sh.z; sv_lds[tid][2] = sh.w;
  }
  __syncthreads();

  // ---- phase 1b: gather per-edge activations
  for (int idx = tid; idx < EB * 160; idx += 256) {
    int e = idx / 160, i = idx - e * 160;
    const float* x = na + (size_t)src_lds[e] * CH;
    float v;
    if (i < 48) v = x[i] * ss_lds[e];
    else if (i < 64) {
      int ii = i - 48;
      v = (x[48 + 3 * ii] * sv_lds[e][0] + x[49 + 3 * ii] * sv_lds[e][1] +
           x[50 + 3 * ii] * sv_lds[e][2]) * INV_SQRT3;
    } else if (i < 112) v = x[i - 64];
    else v = x[48 + (i - 112)];
    a_lds[e * 161 + i] = v;
  }

  // ---- phase 1c: GEMM1  h = relu(ea@w1+b1) -> hscr
  {
    short8 a1[2][4];
#pragma unroll
    for (int mt = 0; mt < 2; mt++)
#pragma unroll
      for (int ks = 0; ks < 4; ks++) {
        const float* src = ea + (size_t)(e0 + mt * 16 + cl) * 128 + ks * 32 + q * 8;
        float4 v0 = *(const float4*)src;
        float4 v1 = *(const float4*)(src + 4);
        union { short8 s; unsigned int u[4]; } pk;
        pk.u[0] = f2bf(v0.x) | ((unsigned)f2bf(v0.y) << 16);
        pk.u[1] = f2bf(v0.z) | ((unsigned)f2bf(v0.w) << 16);
        pk.u[2] = f2bf(v1.x) | ((unsigned)f2bf(v1.y) << 16);
        pk.u[3] = f2bf(v1.z) | ((unsigned)f2bf(v1.w) << 16);
        a1[mt][ks] = pk.s;
      }
    const short8* w1f = (const short8*)(wsu + WSB_W1_U16);
#pragma unroll
    for (int t = 0; t < 2; t++) {
      int nt = wv * 2 + t;
      floatx4 c0 = (floatx4)(0.f), c1 = (floatx4)(0.f);
#pragma unroll
      for (int ks = 0; ks < 4; ks++) {
        short8 bf = w1f[(nt * 4 + ks) * 64 + lane];
        c0 = __builtin_amdgcn_mfma_f32_16x16x32_bf16(a1[0][ks], bf, c0, 0, 0, 0);
        c1 = __builtin_amdgcn_mfma_f32_16x16x32_bf16(a1[1][ks], bf, c1, 0, 0, 0);
      }
      int hcol = nt * 16 + cl;
      float hb = b1g[hcol];
#pragma unroll
      for (int r = 0; r < 4; r++) {
        hscr[(q * 4 + r) * 136 + hcol] = f2bf(fmaxf(c0[r] + hb, 0.f));
        hscr[(16 + q * 4 + r) * 136 + hcol] = f2bf(fmaxf(c1[r] + hb, 0.f));
      }
    }
  }
  __syncthreads();

  // ---- phase 2: A fragments (h) -> registers
  short8 areg[2][4];
#pragma unroll
  for (int mt = 0; mt < 2; mt++)
#pragma unroll
    for (int ks = 0; ks < 4; ks++)
      areg[mt][ks] = *(const short8*)&hscr[(mt * 16 + cl) * 136 + ks * 32 + q * 8];
  __syncthreads();   // all hscr reads done; ovl can be reused

  // zero acc_lds (overlay)
  for (int idx = tid; idx < EB * 113; idx += 256) acc_lds[idx] = 0.f;
  __syncthreads();   // zero visible before any phase-4 atomics

  // ---- phase 3: main loop, per-wave tile ranges, register B prefetch
  const short8* w2f = (const short8*)(wsu + WSB_W2_U16);

#define LOADB(dst, uu) { const short8* _p = w2f + (size_t)(uu) * 256 + lane; \
    dst[0] = _p[0]; dst[1] = _p[64]; dst[2] = _p[128]; dst[3] = _p[192]; }

#define MFMA8(bb, c0, c1) \
    _Pragma("unroll") \
    for (int ks = 0; ks < 4; ks++) { \
      c0 = __builtin_amdgcn_mfma_f32_16x16x32_bf16(areg[0][ks], bb[ks], c0, 0, 0, 0); \
      c1 = __builtin_amdgcn_mfma_f32_16x16x32_bf16(areg[1][ks], bb[ks], c1, 0, 0, 0); }

  if (wv < 3) {
    // ss/vs class: u in [0,192); wave ranges [0,63),[63,126),[126,192)
    const int ng = (wv == 2) ? 22 : 21;
    const int base_ai = wv * 21;
    const int u0 = base_ai * 3;
    float accS[3][2][4];
#pragma unroll
    for (int c = 0; c < 3; c++)
#pragma unroll
      for (int mt = 0; mt < 2; mt++)
#pragma unroll
        for (int r = 0; r < 4; r++) accS[c][mt][r] = 0.f;

    short8 b0[4], b1[4], b2[4];
    LOADB(b0, u0); LOADB(b1, u0 + 1);
    for (int g = 0; g < ng; g++) {
      const int ai = base_ai + g;
      const int u = u0 + 3 * g;
      float av[2][4];
#pragma unroll
      for (int mt = 0; mt < 2; mt++)
#pragma unroll
        for (int r = 0; r < 4; r++)
          av[mt][r] = a_lds[(mt * 16 + q * 4 + r) * 161 + ai];

#define COMP_SS(bb, cidx, uu) { \
      float bias = b2g[(uu) * 16 + cl]; \
      floatx4 c0 = (floatx4)(0.f), c1 = (floatx4)(0.f); \
      MFMA8(bb, c0, c1); \
      _Pragma("unroll") \
      for (int r = 0; r < 4; r++) { \
        accS[cidx][0][r] += av[0][r] * dlrelu(c0[r] + bias); \
        accS[cidx][1][r] += av[1][r] * dlrelu(c1[r] + bias); } }

      LOADB(b2, u + 2); COMP_SS(b0, 0, u);
      LOADB(b0, u + 3); COMP_SS(b1, 1, u + 1);
      LOADB(b1, u + 4); COMP_SS(b2, 2, u + 2);
    }
    // phase 4 (ss): lane owns (e, c*16+cl)
#pragma unroll
    for (int mt = 0; mt < 2; mt++)
#pragma unroll
      for (int r = 0; r < 4; r++) {
        int e = mt * 16 + q * 4 + r;
#pragma unroll
        for (int c = 0; c < 3; c++)
          atomicAdd(&acc_lds[e * 113 + c * 16 + cl], accS[c][mt][r]);
      }
  } else {
    // sv class: u in [192,240); vv class: u in [240,256)
    float accT[2][4], accV[2][4][3];
#pragma unroll
    for (int mt = 0; mt < 2; mt++)
#pragma unroll
      for (int r = 0; r < 4; r++) {
        accT[mt][r] = 0.f;
        accV[mt][r][0] = 0.f; accV[mt][r][1] = 0.f; accV[mt][r][2] = 0.f;
      }
    short8 b0[4], b1[4];
    LOADB(b0, 192);

#define COMP_SV(bb, uu) { \
    float bias = b2g[(uu) * 16 + cl]; \
    const int ai = (uu) - 128; \
    floatx4 c0 = (floatx4)(0.f), c1 = (floatx4)(0.f); \
    MFMA8(bb, c0, c1); \
    _Pragma("unroll") \
    for (int r = 0; r < 4; r++) { \
      accT[0][r] += a_lds[(q * 4 + r) * 161 + ai] * dlrelu(c0[r] + bias); \
      accT[1][r] += a_lds[(16 + q * 4 + r) * 161 + ai] * dlrelu(c1[r] + bias); } }

#define COMP_VV(bb, uu) { \
    float bias = b2g[(uu) * 16 + cl]; \
    const int ab = 3 * (uu) - 608; \
    floatx4 c0 = (floatx4)(0.f), c1 = (floatx4)(0.f); \
    MFMA8(bb, c0, c1); \
    _Pragma("unroll") \
    for (int r = 0; r < 4; r++) { \
      float w0 = dlrelu(c0[r] + bias), w1v = dlrelu(c1[r] + bias); \
      int ba0 = (q * 4 + r) * 161 + ab, ba1 = (16 + q * 4 + r) * 161 + ab; \
      accV[0][r][0] += a_lds[ba0 + 0] * w0; \
      accV[0][r][1] += a_lds[ba0 + 1] * w0; \
      accV[0][r][2] += a_lds[ba0 + 2] * w0; \
      accV[1][r][0] += a_lds[ba1 + 0] * w1v; \
      accV[1][r][1] += a_lds[ba1 + 1] * w1v; \
      accV[1][r][2] += a_lds[ba1 + 2] * w1v; } }

    for (int i = 0; i < 48; i += 2) {
      const int u = 192 + i;
      LOADB(b1, u + 1); COMP_SV(b0, u);
      LOADB(b0, u + 2); COMP_SV(b1, u + 1);
    }
    for (int i = 0; i < 16; i += 2) {
      const int u = 240 + i;
      LOADB(b1, u + 1); COMP_VV(b0, u);
      LOADB(b0, u + 2); COMP_VV(b1, u + 1);   // final prefetch overreads into w1-frag region: in-bounds, unused
    }
    // phase 4 (sv/vv): lane owns (e,48+cl) and (e,64+3cl+m)
#pragma unroll
    for (int mt = 0; mt < 2; mt++)
#pragma unroll
      for (int r = 0; r < 4; r++) {
        int e = mt * 16 + q * 4 + r;
        atomicAdd(&acc_lds[e * 113 + 48 + cl], accT[mt][r]);
#pragma unroll
        for (int m = 0; m < 3; m++)
          atomicAdd(&acc_lds[e * 113 + 64 + 3 * cl + m], accV[mt][r][m]);
      }
  }
  __syncthreads();

  // ---- phase 5: build 96-ch message, scatter to node accumulator
  for (int idx = tid; idx < EB * 96; idx += 256) {
    int e = idx / 96, c = idx - e * 96;
    float val;
    if (c < 48) val = ALPHA * acc_lds[e * 113 + c];
    else {
      int t2 = c - 48; int k = t2 / 3; int m = t2 - k * 3;
      val = ALPHA * (acc_lds[e * 113 + 48 + k] * sv_lds[e][m] +
                     ss_lds[e] * acc_lds[e * 113 + 64 + 3 * k + m]);
    }
    atomicAdd(msg + (size_t)dst_lds[e] * CH + c, val);
  }
}

// ---------------------------------------------------------------------------
__global__ __launch_bounds__(256) void k2_stats(const float* na, float* ws, int ok1) {
  __shared__ float part[112];
  const float* msg = ws + OFF_MSG;
  float* st = ws + OFF_ST;
  for (int i = threadIdx.x; i < 112; i += 256) part[i] = 0.f;
  __syncthreads();
  if (ok1) {
    int stride = gridDim.x * 256;
    for (int idx = blockIdx.x * 256 + threadIdx.x; idx < NNODES * CH; idx += stride) {
      int c = idx % CH;
      float t = msg[idx] + na[idx];
      if (c < 48) { atomicAdd(&part[c], t); atomicAdd(&part[48 + c], t * t); }
      else { int k = (c - 48) / 3; atomicAdd(&part[96 + k], t * t); }
    }
    __syncthreads();
    for (int i = threadIdx.x; i < 112; i += 256) atomicAdd(&st[i], part[i]);
  }
}

// ---------------------------------------------------------------------------
__global__ __launch_bounds__(256) void k3_final(const float* na, const float* bnw,
                                                const float* bnb, const float* ws,
                                                float* out, int ok1) {
  __shared__ float mean_s[48], scale_s[48], bias_s[48], scale_v[16];
  const float* msg = ws + OFF_MSG;
  const float* st = ws + OFF_ST;
  const int tid = threadIdx.x;
  if (tid < 48) {
    float s1 = ok1 ? fin(st[tid]) : 0.f;
    float s2 = ok1 ? fin(st[48 + tid]) : 0.f;
    float m = s1 * (1.f / NNODES);
    float var = fmaxf(s2 * (1.f / NNODES) - m * m, 0.f);
    mean_s[tid] = m;
    scale_s[tid] = rsqrtf(var + EPS) * bnw[tid];
    bias_s[tid] = bnb[tid];
  } else if (tid < 64) {
    int k = tid - 48;
    float s2 = ok1 ? fin(st[96 + k]) : 0.f;
    scale_v[k] = rsqrtf(fmaxf(s2 * (1.f / (3.f * NNODES)), 0.f) + EPS) * bnw[48 + k];
  }
  __syncthreads();
  int stride = gridDim.x * 256;
  for (int idx = blockIdx.x * 256 + tid; idx < NNODES * CH; idx += stride) {
    int c = idx % CH;
    float t = (ok1 ? msg[idx] : 0.f) + na[idx];
    float o;
    if (c < 48) o = (t - mean_s[c]) * scale_s[c] + bias_s[c];
    else { int k = (c - 48) / 3; o = t * scale_v[k]; }
    out[idx] = fin(o);
  }
}

// ---------------------------------------------------------------------------
extern "C" void kernel_launch(void* const* d_in, const int* in_sizes, int n_in,
                              void* d_out, int out_size, void* d_ws, size_t ws_size,
                              hipStream_t stream) {
  const float* na  = (const float*)d_in[0];
  const int* eidx  = (const int*)d_in[1];
  const float* ea  = (const float*)d_in[2];
  const float* esh = (const float*)d_in[3];
  const float* w1  = (const float*)d_in[4];
  const float* b1  = (const float*)d_in[5];
  const float* w2  = (const float*)d_in[6];
  const float* b2  = (const float*)d_in[7];
  const float* bnw = (const float*)d_in[8];
  const float* bnb = (const float*)d_in[9];
  float* out = (float*)d_out;
  float* ws = (float*)d_ws;
  const int ok1 = (ws_size >= (size_t)WS_BYTES1) ? 1 : 0;
  const int ok2 = (ws_size >= (size_t)WS_BYTES2) ? 1 : 0;

  hipLaunchKernelGGL(k0_prep,  dim3(256), dim3(256), 0, stream, w1, w2, ws, ok1, ok2);
  hipLaunchKernelGGL(k1_fused, dim3(NBLK), dim3(256), 0, stream,
                     eidx, na, ea, esh, b1, b2, ws, ok2);
  hipLaunchKernelGGL(k2_stats, dim3(512), dim3(256), 0, stream, na, ws, ok1);
  hipLaunchKernelGGL(k3_final, dim3(512), dim3(256), 0, stream, na, bnw, bnb, ws, out, ok1);
}